// Round 2
// baseline (3090.506 us; speedup 1.0000x reference)
//
#include <hip/hip_runtime.h>
#include <stdint.h>

// ---------------------------------------------------------------------------
// GCN 2-layer: out = Ahat( dropout(elu( Ahat(x@W1)+b1 )) @ W2 ) + b2
// Ahat = D^-1/2 (A+I) D^-1/2
// dropout mask = jax threefry2x32, key(42), p=0.25, PARTITIONABLE path:
//   j = flat index; (b1,b2) = threefry(key, (j>>32, j&0xffffffff)); bits=b1^b2
// ---------------------------------------------------------------------------

// ---------------- Threefry-2x32, key = (0, 42), 20 rounds ------------------
__device__ __forceinline__ void tf_round(uint32_t& x0, uint32_t& x1, int r) {
  x0 += x1;
  x1 = (x1 << r) | (x1 >> (32 - r));
  x1 ^= x0;
}

__device__ __forceinline__ void threefry_0_42(uint32_t c0, uint32_t c1,
                                              uint32_t& o0, uint32_t& o1) {
  const uint32_t ks0 = 0u;
  const uint32_t ks1 = 42u;
  const uint32_t ks2 = 0x1BD11BDAu ^ 0u ^ 42u;
  uint32_t x0 = c0 + ks0;
  uint32_t x1 = c1 + ks1;
  tf_round(x0, x1, 13); tf_round(x0, x1, 15); tf_round(x0, x1, 26); tf_round(x0, x1, 6);
  x0 += ks1; x1 += ks2 + 1u;
  tf_round(x0, x1, 17); tf_round(x0, x1, 29); tf_round(x0, x1, 16); tf_round(x0, x1, 24);
  x0 += ks2; x1 += ks0 + 2u;
  tf_round(x0, x1, 13); tf_round(x0, x1, 15); tf_round(x0, x1, 26); tf_round(x0, x1, 6);
  x0 += ks0; x1 += ks1 + 3u;
  tf_round(x0, x1, 17); tf_round(x0, x1, 29); tf_round(x0, x1, 16); tf_round(x0, x1, 24);
  x0 += ks1; x1 += ks2 + 4u;
  tf_round(x0, x1, 13); tf_round(x0, x1, 15); tf_round(x0, x1, 26); tf_round(x0, x1, 6);
  x0 += ks2; x1 += ks0 + 5u;
  o0 = x0; o1 = x1;
}

// ---------------- degree + dinv --------------------------------------------
__global__ void k_deg(const int* __restrict__ dst, int E, int* __restrict__ deg) {
  int e = blockIdx.x * blockDim.x + threadIdx.x;
  if (e < E) atomicAdd(&deg[dst[e]], 1);
}

__global__ void k_dinv(const int* __restrict__ deg, float* __restrict__ dinv, int N) {
  int n = blockIdx.x * blockDim.x + threadIdx.x;
  if (n < N) {
    float d = (float)(deg[n] + 1);  // +1 self loop
    dinv[n] = 1.0f / sqrtf(d);
  }
}

// ---------------- GEMM1: h = x @ W1  (fp32, [M,512]@[512,256], NO bias) ----
__global__ __launch_bounds__(256) void k_gemm1(
    const float* __restrict__ A,    // [M,512]
    const float* __restrict__ B,    // [512,256]
    float* __restrict__ C,          // [M,256]
    int M) {
  const int K = 512, N = 256;
  __shared__ __align__(16) float As[16][68];  // [k][m], 272B row = 17*16B
  __shared__ __align__(16) float Bs[16][64];  // [k][n]

  const int tid = threadIdx.x;
  const int tx = tid & 15;   // col group (4 cols)
  const int ty = tid >> 4;   // row group (4 rows)
  const int row0 = blockIdx.x * 64;
  const int col0 = blockIdx.y * 64;

  const int arow = tid >> 2, acg = tid & 3;   // A-tile: 64 rows x 4 float4
  const int brow = tid >> 4, bcg = tid & 15;  // B-tile: 16 rows x 16 float4

  float acc[4][4] = {};

  const int grA = row0 + arow;
  const float* Aptr = A + (size_t)grA * K + acg * 4;
  const float* Bptr = B + (size_t)brow * N + col0 + bcg * 4;

  for (int k0 = 0; k0 < K; k0 += 16) {
    float4 a4 = make_float4(0.f, 0.f, 0.f, 0.f);
    if (grA < M) a4 = *(const float4*)(Aptr + k0);
    float4 b4 = *(const float4*)(Bptr + (size_t)k0 * N);

    __syncthreads();  // previous tile consumed
    As[acg * 4 + 0][arow] = a4.x;
    As[acg * 4 + 1][arow] = a4.y;
    As[acg * 4 + 2][arow] = a4.z;
    As[acg * 4 + 3][arow] = a4.w;
    *(float4*)&Bs[brow][bcg * 4] = b4;
    __syncthreads();

#pragma unroll
    for (int k = 0; k < 16; ++k) {
      float4 av = *(const float4*)&As[k][ty * 4];
      float4 bv = *(const float4*)&Bs[k][tx * 4];
      acc[0][0] += av.x * bv.x; acc[0][1] += av.x * bv.y; acc[0][2] += av.x * bv.z; acc[0][3] += av.x * bv.w;
      acc[1][0] += av.y * bv.x; acc[1][1] += av.y * bv.y; acc[1][2] += av.y * bv.z; acc[1][3] += av.y * bv.w;
      acc[2][0] += av.z * bv.x; acc[2][1] += av.z * bv.y; acc[2][2] += av.z * bv.z; acc[2][3] += av.z * bv.w;
      acc[3][0] += av.w * bv.x; acc[3][1] += av.w * bv.y; acc[3][2] += av.w * bv.z; acc[3][3] += av.w * bv.w;
    }
  }

#pragma unroll
  for (int i = 0; i < 4; ++i) {
    int r = row0 + ty * 4 + i;
    if (r < M) {
      float4 o;
      o.x = acc[i][0];
      o.y = acc[i][1];
      o.z = acc[i][2];
      o.w = acc[i][3];
      *(float4*)(C + (size_t)r * N + col0 + tx * 4) = o;
    }
  }
}

// ---------------- agg init with self-loop term: agg = dinv^2 * h -----------
__global__ void k_selfloop(const float* __restrict__ h, const float* __restrict__ dinv,
                           float* __restrict__ agg, int N) {
  int t = blockIdx.x * blockDim.x + threadIdx.x;
  if (t >= N * 64) return;           // N*64 float4 = N*256 floats
  int n = t >> 6;
  float a = dinv[n]; a *= a;
  float4 v = ((const float4*)h)[t];
  v.x *= a; v.y *= a; v.z *= a; v.w *= a;
  ((float4*)agg)[t] = v;
}

// ---------------- edge scatter layer 1 (one wave per edge) -----------------
__global__ __launch_bounds__(256) void k_scatter1(
    const int* __restrict__ src, const int* __restrict__ dst,
    const float* __restrict__ dinv, const float* __restrict__ h,
    float* __restrict__ agg, int E) {
  int t = blockIdx.x * blockDim.x + threadIdx.x;
  int e = t >> 6;
  if (e >= E) return;
  int lane = t & 63;
  int s = src[e], d = dst[e];
  float norm = dinv[s] * dinv[d];
  float4 v = *(const float4*)(h + ((size_t)s << 8) + (lane << 2));
  float* ap = agg + ((size_t)d << 8) + (lane << 2);
  atomicAdd(ap + 0, v.x * norm);
  atomicAdd(ap + 1, v.y * norm);
  atomicAdd(ap + 2, v.z * norm);
  atomicAdd(ap + 3, v.w * norm);
}

// ------- fused: +b1 -> elu -> dropout(threefry partitionable) -> dot W2 ----
// one wave per node; lane covers 4 features; flat j = n*256 + f < 2^32
// bits[j] = o0 ^ o1 of threefry(key, (0, j)); u = bitcast((bits>>9)|1.0f)-1
__global__ __launch_bounds__(256) void k_fused(
    const float* __restrict__ agg, const float* __restrict__ b1,
    const float* __restrict__ W2, float* __restrict__ z, int N) {
  int wave = (blockIdx.x * blockDim.x + threadIdx.x) >> 6;
  int lane = threadIdx.x & 63;
  if (wave >= N) return;
  int f0 = lane << 2;

  float4 v  = *(const float4*)(agg + ((size_t)wave << 8) + f0);
  float4 bb = *(const float4*)(b1 + f0);
  float4 w  = *(const float4*)(W2 + f0);

  float acc = 0.f;
  uint32_t jbase = ((uint32_t)wave << 8) + (uint32_t)f0;
#pragma unroll
  for (int i = 0; i < 4; ++i) {
    uint32_t r0, r1;
    threefry_0_42(0u, jbase + i, r0, r1);  // ctr = (hi=0, lo=j)
    uint32_t bits = r0 ^ r1;
    float u = __uint_as_float((bits >> 9) | 0x3f800000u) - 1.0f;
    float va = (&v.x)[i] + (&bb.x)[i];
    float ea = va > 0.f ? va : expm1f(va);
    float ha = (u < 0.75f) ? (ea * (1.0f / 0.75f)) : 0.f;
    acc += ha * (&w.x)[i];
  }
#pragma unroll
  for (int off = 32; off > 0; off >>= 1) acc += __shfl_down(acc, off, 64);
  if (lane == 0) z[wave] = acc;
}

// ---------------- layer-2 output: init + edge scatter (scalar) -------------
__global__ void k_out_init(const float* __restrict__ z, const float* __restrict__ dinv,
                           const float* __restrict__ b2, float* __restrict__ out, int N) {
  int n = blockIdx.x * blockDim.x + threadIdx.x;
  if (n < N) {
    float a = dinv[n];
    out[n] = b2[0] + a * a * z[n];
  }
}

__global__ void k_scatter2(const int* __restrict__ src, const int* __restrict__ dst,
                           const float* __restrict__ dinv, const float* __restrict__ z,
                           float* __restrict__ out, int E) {
  int e = blockIdx.x * blockDim.x + threadIdx.x;
  if (e < E) {
    int s = src[e], d = dst[e];
    atomicAdd(&out[d], dinv[s] * dinv[d] * z[s]);
  }
}

// ---------------------------------------------------------------------------
extern "C" void kernel_launch(void* const* d_in, const int* in_sizes, int n_in,
                              void* d_out, int out_size, void* d_ws, size_t ws_size,
                              hipStream_t stream) {
  const float* x  = (const float*)d_in[0];
  const int*   ei = (const int*)d_in[1];   // [2,E] int32
  const float* W1 = (const float*)d_in[2];
  const float* b1 = (const float*)d_in[3];
  const float* W2 = (const float*)d_in[4];
  const float* b2 = (const float*)d_in[5];
  float* out = (float*)d_out;

  const int E = in_sizes[1] / 2;
  const int N = in_sizes[0] / 512;  // 50000
  const int* src = ei;
  const int* dst = ei + E;

  char* ws = (char*)d_ws;
  size_t off = 0;
  auto alloc = [&](size_t bytes) -> void* {
    void* p = ws + off;
    off += (bytes + 255) & ~(size_t)255;
    return p;
  };
  int*   deg  = (int*)  alloc((size_t)N * 4);
  float* dinv = (float*)alloc((size_t)N * 4);
  float* h    = (float*)alloc((size_t)N * 256 * 4);  // 51.2 MB
  float* agg  = (float*)alloc((size_t)N * 256 * 4);  // 51.2 MB
  float* z    = (float*)alloc((size_t)N * 4);

  hipMemsetAsync(deg, 0, (size_t)N * 4, stream);
  k_deg<<<(E + 255) / 256, 256, 0, stream>>>(dst, E, deg);
  k_dinv<<<(N + 255) / 256, 256, 0, stream>>>(deg, dinv, N);

  dim3 g1((N + 63) / 64, 4);
  k_gemm1<<<g1, 256, 0, stream>>>(x, W1, h, N);

  k_selfloop<<<(N * 64 + 255) / 256, 256, 0, stream>>>(h, dinv, agg, N);
  k_scatter1<<<(int)(((size_t)E * 64 + 255) / 256), 256, 0, stream>>>(src, dst, dinv, h, agg, E);

  k_fused<<<(N * 64 + 255) / 256, 256, 0, stream>>>(agg, b1, W2, z, N);
  k_out_init<<<(N + 255) / 256, 256, 0, stream>>>(z, dinv, b2, out, N);
  k_scatter2<<<(E + 255) / 256, 256, 0, stream>>>(src, dst, dinv, z, out, E);
}

// Round 3
// 644.469 us; speedup vs baseline: 4.7954x; 4.7954x over previous
//
#include <hip/hip_runtime.h>
#include <stdint.h>

// ---------------------------------------------------------------------------
// GCN 2-layer: out = Ahat( dropout(elu( Ahat(x@W1)+b1 )) @ W2 ) + b2
// Ahat = D^-1/2 (A+I) D^-1/2
// dropout = jax threefry2x32 key(42), p=0.25, partitionable path:
//   bits[j] = o0^o1 of threefry(key,(0,j)); u = bitcast((bits>>9)|1.0f)-1
// Aggregation strategy: CSR-by-dst gather (R2 showed scatter-atomics = 86%).
// ---------------------------------------------------------------------------

// ---------------- Threefry-2x32, key = (0, 42), 20 rounds ------------------
__device__ __forceinline__ void tf_round(uint32_t& x0, uint32_t& x1, int r) {
  x0 += x1;
  x1 = (x1 << r) | (x1 >> (32 - r));
  x1 ^= x0;
}

__device__ __forceinline__ void threefry_0_42(uint32_t c0, uint32_t c1,
                                              uint32_t& o0, uint32_t& o1) {
  const uint32_t ks0 = 0u;
  const uint32_t ks1 = 42u;
  const uint32_t ks2 = 0x1BD11BDAu ^ 0u ^ 42u;
  uint32_t x0 = c0 + ks0;
  uint32_t x1 = c1 + ks1;
  tf_round(x0, x1, 13); tf_round(x0, x1, 15); tf_round(x0, x1, 26); tf_round(x0, x1, 6);
  x0 += ks1; x1 += ks2 + 1u;
  tf_round(x0, x1, 17); tf_round(x0, x1, 29); tf_round(x0, x1, 16); tf_round(x0, x1, 24);
  x0 += ks2; x1 += ks0 + 2u;
  tf_round(x0, x1, 13); tf_round(x0, x1, 15); tf_round(x0, x1, 26); tf_round(x0, x1, 6);
  x0 += ks0; x1 += ks1 + 3u;
  tf_round(x0, x1, 17); tf_round(x0, x1, 29); tf_round(x0, x1, 16); tf_round(x0, x1, 24);
  x0 += ks1; x1 += ks2 + 4u;
  tf_round(x0, x1, 13); tf_round(x0, x1, 15); tf_round(x0, x1, 26); tf_round(x0, x1, 6);
  x0 += ks2; x1 += ks0 + 5u;
  o0 = x0; o1 = x1;
}

// ---------------- degree -----------------------------------------------
__global__ void k_deg(const int* __restrict__ dst, int E, int* __restrict__ deg) {
  int e = blockIdx.x * blockDim.x + threadIdx.x;
  if (e < E) atomicAdd(&deg[dst[e]], 1);
}

__global__ void k_dinv(const int* __restrict__ deg, float* __restrict__ dinv, int N) {
  int n = blockIdx.x * blockDim.x + threadIdx.x;
  if (n < N) {
    float d = (float)(deg[n] + 1);  // +1 self loop
    dinv[n] = 1.0f / sqrtf(d);
  }
}

// ---------------- exclusive scan (single block, 1024 thr) ------------------
__global__ __launch_bounds__(1024) void k_scan(const int* __restrict__ deg,
                                               int* __restrict__ rowptr, int N) {
  __shared__ int smem[1024];
  __shared__ int base_s;
  int tid = threadIdx.x;
  if (tid == 0) base_s = 0;
  __syncthreads();
  for (int start = 0; start < N; start += 1024) {
    int i = start + tid;
    int v = (i < N) ? deg[i] : 0;
    smem[tid] = v;
    __syncthreads();
#pragma unroll
    for (int off = 1; off < 1024; off <<= 1) {
      int t = (tid >= off) ? smem[tid - off] : 0;
      __syncthreads();
      smem[tid] += t;
      __syncthreads();
    }
    int incl = smem[tid];
    int base = base_s;
    if (i < N) rowptr[i] = base + incl - v;  // exclusive
    __syncthreads();
    if (tid == 1023) base_s = base + incl;
    __syncthreads();
  }
  if (tid == 0) rowptr[N] = base_s;
}

// ---------------- bucket edges by dst --------------------------------------
__global__ void k_bucket(const int* __restrict__ src, const int* __restrict__ dst,
                         int* __restrict__ cursor, int* __restrict__ csr_src, int E) {
  int e = blockIdx.x * blockDim.x + threadIdx.x;
  if (e < E) {
    int pos = atomicAdd(&cursor[dst[e]], 1);
    csr_src[pos] = src[e];
  }
}

// ---------------- GEMM1: h = x @ W1  (fp32, [M,512]@[512,256]) -------------
__global__ __launch_bounds__(256) void k_gemm1(
    const float* __restrict__ A,    // [M,512]
    const float* __restrict__ B,    // [512,256]
    float* __restrict__ C,          // [M,256]
    int M) {
  const int K = 512, N = 256;
  __shared__ __align__(16) float As[16][68];  // [k][m], padded
  __shared__ __align__(16) float Bs[16][64];  // [k][n]

  const int tid = threadIdx.x;
  const int tx = tid & 15;
  const int ty = tid >> 4;
  const int row0 = blockIdx.x * 64;
  const int col0 = blockIdx.y * 64;

  const int arow = tid >> 2, acg = tid & 3;
  const int brow = tid >> 4, bcg = tid & 15;

  float acc[4][4] = {};

  const int grA = row0 + arow;
  const float* Aptr = A + (size_t)grA * K + acg * 4;
  const float* Bptr = B + (size_t)brow * N + col0 + bcg * 4;

  for (int k0 = 0; k0 < K; k0 += 16) {
    float4 a4 = make_float4(0.f, 0.f, 0.f, 0.f);
    if (grA < M) a4 = *(const float4*)(Aptr + k0);
    float4 b4 = *(const float4*)(Bptr + (size_t)k0 * N);

    __syncthreads();
    As[acg * 4 + 0][arow] = a4.x;
    As[acg * 4 + 1][arow] = a4.y;
    As[acg * 4 + 2][arow] = a4.z;
    As[acg * 4 + 3][arow] = a4.w;
    *(float4*)&Bs[brow][bcg * 4] = b4;
    __syncthreads();

#pragma unroll
    for (int k = 0; k < 16; ++k) {
      float4 av = *(const float4*)&As[k][ty * 4];
      float4 bv = *(const float4*)&Bs[k][tx * 4];
      acc[0][0] += av.x * bv.x; acc[0][1] += av.x * bv.y; acc[0][2] += av.x * bv.z; acc[0][3] += av.x * bv.w;
      acc[1][0] += av.y * bv.x; acc[1][1] += av.y * bv.y; acc[1][2] += av.y * bv.z; acc[1][3] += av.y * bv.w;
      acc[2][0] += av.z * bv.x; acc[2][1] += av.z * bv.y; acc[2][2] += av.z * bv.z; acc[2][3] += av.z * bv.w;
      acc[3][0] += av.w * bv.x; acc[3][1] += av.w * bv.y; acc[3][2] += av.w * bv.z; acc[3][3] += av.w * bv.w;
    }
  }

#pragma unroll
  for (int i = 0; i < 4; ++i) {
    int r = row0 + ty * 4 + i;
    if (r < M) {
      float4 o = make_float4(acc[i][0], acc[i][1], acc[i][2], acc[i][3]);
      *(float4*)(C + (size_t)r * N + col0 + tx * 4) = o;
    }
  }
}

// ------- gather layer 1: agg[d] = dinv_d^2 h[d] + Σ_in dinv_s dinv_d h[s] --
// one wave per dst node, lane covers 4 features (256 = 64*4)
__global__ __launch_bounds__(256) void k_gather1(
    const int* __restrict__ rowptr, const int* __restrict__ csr_src,
    const float* __restrict__ dinv, const float* __restrict__ h,
    float* __restrict__ agg, int N) {
  int wave = (blockIdx.x * blockDim.x + threadIdx.x) >> 6;
  int lane = threadIdx.x & 63;
  if (wave >= N) return;
  int d = wave;
  float dd = dinv[d];
  int beg = rowptr[d], end = rowptr[d + 1];

  float4 v = *(const float4*)(h + ((size_t)d << 8) + (lane << 2));
  float sw = dd * dd;
  float4 acc = make_float4(v.x * sw, v.y * sw, v.z * sw, v.w * sw);

  for (int e = beg; e < end; ++e) {
    int s = csr_src[e];
    float norm = dinv[s] * dd;
    float4 hv = *(const float4*)(h + ((size_t)s << 8) + (lane << 2));
    acc.x += norm * hv.x;
    acc.y += norm * hv.y;
    acc.z += norm * hv.z;
    acc.w += norm * hv.w;
  }
  *(float4*)(agg + ((size_t)d << 8) + (lane << 2)) = acc;
}

// ------- fused: +b1 -> elu -> dropout(threefry) -> dot W2 ------------------
__global__ __launch_bounds__(256) void k_fused(
    const float* __restrict__ agg, const float* __restrict__ b1,
    const float* __restrict__ W2, float* __restrict__ z, int N) {
  int wave = (blockIdx.x * blockDim.x + threadIdx.x) >> 6;
  int lane = threadIdx.x & 63;
  if (wave >= N) return;
  int f0 = lane << 2;

  float4 v  = *(const float4*)(agg + ((size_t)wave << 8) + f0);
  float4 bb = *(const float4*)(b1 + f0);
  float4 w  = *(const float4*)(W2 + f0);

  float acc = 0.f;
  uint32_t jbase = ((uint32_t)wave << 8) + (uint32_t)f0;
#pragma unroll
  for (int i = 0; i < 4; ++i) {
    uint32_t r0, r1;
    threefry_0_42(0u, jbase + i, r0, r1);  // ctr = (hi=0, lo=j)
    uint32_t bits = r0 ^ r1;
    float u = __uint_as_float((bits >> 9) | 0x3f800000u) - 1.0f;
    float va = (&v.x)[i] + (&bb.x)[i];
    float ea = va > 0.f ? va : expm1f(va);
    float ha = (u < 0.75f) ? (ea * (1.0f / 0.75f)) : 0.f;
    acc += ha * (&w.x)[i];
  }
#pragma unroll
  for (int off = 32; off > 0; off >>= 1) acc += __shfl_down(acc, off, 64);
  if (lane == 0) z[wave] = acc;
}

// ------- gather layer 2 (scalar feature): one wave per node ----------------
// out[d] = b2 + dd^2 z[d] + dd * Σ_in dinv[s] z[s]
__global__ __launch_bounds__(256) void k_gather2(
    const int* __restrict__ rowptr, const int* __restrict__ csr_src,
    const float* __restrict__ dinv, const float* __restrict__ z,
    const float* __restrict__ b2, float* __restrict__ out, int N) {
  int wave = (blockIdx.x * blockDim.x + threadIdx.x) >> 6;
  int lane = threadIdx.x & 63;
  if (wave >= N) return;
  int d = wave;
  float dd = dinv[d];
  int beg = rowptr[d], end = rowptr[d + 1];

  float acc = 0.f;
  for (int e = beg + lane; e < end; e += 64) {
    int s = csr_src[e];
    acc += dinv[s] * z[s];
  }
#pragma unroll
  for (int off = 32; off > 0; off >>= 1) acc += __shfl_down(acc, off, 64);
  if (lane == 0) out[d] = b2[0] + dd * dd * z[d] + dd * acc;
}

// ---------------------------------------------------------------------------
extern "C" void kernel_launch(void* const* d_in, const int* in_sizes, int n_in,
                              void* d_out, int out_size, void* d_ws, size_t ws_size,
                              hipStream_t stream) {
  const float* x  = (const float*)d_in[0];
  const int*   ei = (const int*)d_in[1];   // [2,E] int32
  const float* W1 = (const float*)d_in[2];
  const float* b1 = (const float*)d_in[3];
  const float* W2 = (const float*)d_in[4];
  const float* b2 = (const float*)d_in[5];
  float* out = (float*)d_out;

  const int E = in_sizes[1] / 2;
  const int N = in_sizes[0] / 512;  // 50000
  const int* src = ei;
  const int* dst = ei + E;

  char* ws = (char*)d_ws;
  size_t off = 0;
  auto alloc = [&](size_t bytes) -> void* {
    void* p = ws + off;
    off += (bytes + 255) & ~(size_t)255;
    return p;
  };
  int*   deg     = (int*)  alloc((size_t)N * 4);
  int*   rowptr  = (int*)  alloc((size_t)(N + 1) * 4);
  int*   cursor  = (int*)  alloc((size_t)N * 4);
  int*   csr_src = (int*)  alloc((size_t)E * 4);         // 3.2 MB
  float* dinv    = (float*)alloc((size_t)N * 4);
  float* h       = (float*)alloc((size_t)N * 256 * 4);   // 51.2 MB
  float* agg     = (float*)alloc((size_t)N * 256 * 4);   // 51.2 MB
  float* z       = (float*)alloc((size_t)N * 4);

  hipMemsetAsync(deg, 0, (size_t)N * 4, stream);
  k_deg<<<(E + 255) / 256, 256, 0, stream>>>(dst, E, deg);
  k_dinv<<<(N + 255) / 256, 256, 0, stream>>>(deg, dinv, N);
  k_scan<<<1, 1024, 0, stream>>>(deg, rowptr, N);
  hipMemcpyAsync(cursor, rowptr, (size_t)N * 4, hipMemcpyDeviceToDevice, stream);
  k_bucket<<<(E + 255) / 256, 256, 0, stream>>>(src, dst, cursor, csr_src, E);

  dim3 g1((N + 63) / 64, 4);
  k_gemm1<<<g1, 256, 0, stream>>>(x, W1, h, N);

  k_gather1<<<(N * 64 + 255) / 256, 256, 0, stream>>>(rowptr, csr_src, dinv, h, agg, N);
  k_fused<<<(N * 64 + 255) / 256, 256, 0, stream>>>(agg, b1, W2, z, N);
  k_gather2<<<(N * 64 + 255) / 256, 256, 0, stream>>>(rowptr, csr_src, dinv, z, b2, out, N);
}